// Round 12
// baseline (1992.269 us; speedup 1.0000x reference)
//
#include <hip/hip_runtime.h>
#include <hip/hip_bf16.h>
#include <math.h>

#define N_NODES 100000
#define N_EDGES 1000000
#define IN_DIM 128
#define HID 64
#define NET 4
#define STEPS 5
#define G_GRAPHS 128
#define LBL 10
#define NGRP 6250        // N_NODES / 16 (exact)
#define NBKT 1024        // CSR buckets of 128 nodes
#define TILE_E 8192      // edges per bscatter block

typedef __attribute__((ext_vector_type(8))) short short8;
typedef __attribute__((ext_vector_type(4))) float f32x4;
typedef unsigned short ushort_t;

__device__ inline ushort_t f2bf(float v) {
    __hip_bfloat16 b = __float2bfloat16(v);
    return __builtin_bit_cast(ushort_t, b);
}
__device__ inline float bf2f(ushort_t u) {
    __hip_bfloat16 b = __builtin_bit_cast(__hip_bfloat16, u);
    return __bfloat162float(b);
}

// h state: hrow (hi bf16) + lrow (lo bf16), each [node][64] row-major, double-buffered.
// adj payload: src(0..16) | et<<20 | (node&31)<<22  (blocks are 32-node aligned).
// row_ptr2[n*4+t] = per-(node,etype) segment starts (for counts + block edge ranges).

// ---------------- pack BC: We -> [24 sl][4 ct][64 lane][8 j] bf16 ----------------
__global__ void k_pack_bc(const float* __restrict__ We, ushort_t* __restrict__ BC) {
    int idx = blockIdx.x * blockDim.x + threadIdx.x;   // 49152
    if (idx >= 24 * 4 * 64 * 8) return;
    int j = idx & 7, lane = (idx >> 3) & 63, ct = (idx >> 9) & 3, sl = idx >> 11;
    int g = lane >> 4, u = lane & 15;
    int p = sl >> 3, ks = sl & 7;
    int k = ks * 32 + g * 8 + j;
    int t = k >> 6, d = k & 63;
    int o = ct * 16 + u;
    float val = We[t * 4096 + o * 64 + d];
    ushort_t hi = f2bf(val);
    BC[idx] = (p < 2) ? hi : f2bf(val - bf2f(hi));
}

// ---------------- pack B2: GRU fused weight -> [12][16][4][16][8] bf16 ----------------
__global__ void k_pack_b2(const float* __restrict__ W_ih, const float* __restrict__ b_ih,
                          const float* __restrict__ W_hh, const float* __restrict__ b_hh,
                          ushort_t* __restrict__ B2, float* __restrict__ bg2) {
    int idx = blockIdx.x * blockDim.x + threadIdx.x;
    if (idx >= 12 * 16 * 4 * 16 * 8) return;
    int j = idx & 7, u = (idx >> 3) & 15, g = (idx >> 7) & 3, ct = (idx >> 9) & 15, s = idx >> 13;
    int m = ct * 16 + u;
    int q = m >> 6, gate = (m >> 4) & 3, c = q * 16 + (m & 15);
    int k = (s & 3) * 32 + g * 8 + j;
    float val;
    if (gate == 0)      { int jr = c;        val = (k < 64) ? W_ih[jr * 64 + k] : W_hh[jr * 64 + k - 64]; }
    else if (gate == 1) { int jr = 64 + c;   val = (k < 64) ? W_ih[jr * 64 + k] : W_hh[jr * 64 + k - 64]; }
    else if (gate == 2) { int jr = 128 + c;  val = (k < 64) ? W_ih[jr * 64 + k] : 0.f; }
    else                { int jr = 128 + c;  val = (k < 64) ? 0.f : W_hh[jr * 64 + k - 64]; }
    ushort_t hi = f2bf(val);
    B2[idx] = (s < 8) ? hi : f2bf(val - bf2f(hi));
    if (s == 0 && g == 0 && j == 0) {
        float bv;
        if (gate == 0)      bv = b_ih[c] + b_hh[c];
        else if (gate == 1) bv = b_ih[64 + c] + b_hh[64 + c];
        else if (gate == 2) bv = b_ih[128 + c];
        else                bv = b_hh[128 + c];
        bg2[m] = bv;
    }
}

// ---------------- pack BIN: W_in -> [12 slices][4 ct][64 lane][8 j] bf16 ----------------
__global__ void k_pack_bin(const float* __restrict__ W_in, ushort_t* __restrict__ BIN) {
    int idx = blockIdx.x * blockDim.x + threadIdx.x; // 24576
    if (idx >= 24576) return;
    int j = idx & 7, lu = (idx >> 3) & 63, ct = (idx >> 9) & 3, s = idx >> 11;
    int g = lu >> 4, u = lu & 15;
    int m = ct * 16 + u;
    int k = (s & 3) * 32 + g * 8 + j;
    float val = W_in[m * 128 + k];
    ushort_t hi = f2bf(val);
    BIN[idx] = (s < 8) ? hi : f2bf(val - bf2f(hi));
}

// ---------------- h0 = x @ W_in.T + b_in via MFMA; writes hrow + lrow ----------------
__global__ __launch_bounds__(256) void k_linear_in(const float* __restrict__ x,
        const ushort_t* __restrict__ BIN, const float* __restrict__ b_in,
        ushort_t* __restrict__ hrow, ushort_t* __restrict__ lrow) {
    __shared__ float hlds[4][16 * 68];
    int tid = threadIdx.x;
    int lane = tid & 63, wp = tid >> 6;
    int g = lane >> 4, u = lane & 15;
    int grp = blockIdx.x * 4 + wp;
    bool ok = grp < NGRP;
    int row = ok ? (grp * 16 + u) : 0;
    short8 xhi[4], xlo[4];
    #pragma unroll
    for (int ks = 0; ks < 4; ++ks) {
        const float* xp = &x[(size_t)row * 128 + ks * 32 + g * 8];
        float4 v0 = ok ? *(const float4*)xp : make_float4(0.f, 0.f, 0.f, 0.f);
        float4 v1 = ok ? *(const float4*)(xp + 4) : make_float4(0.f, 0.f, 0.f, 0.f);
        float vv[8] = {v0.x, v0.y, v0.z, v0.w, v1.x, v1.y, v1.z, v1.w};
        #pragma unroll
        for (int j = 0; j < 8; ++j) {
            ushort_t hh = f2bf(vv[j]);
            xhi[ks][j] = (short)hh;
            xlo[ks][j] = (short)f2bf(vv[j] - bf2f(hh));
        }
    }
    f32x4 zero = {0.f, 0.f, 0.f, 0.f};
    f32x4 acc[4] = {zero, zero, zero, zero};
    #pragma unroll
    for (int s = 0; s < 12; ++s) {
        int ks = s & 3;
        short8 af = (s < 4) ? xhi[ks] : (s < 8) ? xlo[ks] : xhi[ks];
        #pragma unroll
        for (int ct = 0; ct < 4; ++ct) {
            short8 bf = *(const short8*)&BIN[((size_t)(s * 4 + ct) * 64 + lane) * 8];
            acc[ct] = __builtin_amdgcn_mfma_f32_16x16x32_bf16(af, bf, acc[ct], 0, 0, 0);
        }
    }
    #pragma unroll
    for (int ct = 0; ct < 4; ++ct) {
        float bo = b_in[ct * 16 + u];
        #pragma unroll
        for (int j = 0; j < 4; ++j)
            hlds[wp][(g * 4 + j) * 68 + ct * 16 + u] = acc[ct][j] + bo;
    }
    __syncthreads();
    #pragma unroll
    for (int k = 0; k < 4; ++k) {
        int bi = g + 4 * k;      // 0..15
        short8 ov;
        #pragma unroll
        for (int j = 0; j < 8; ++j) {
            float v = hlds[wp][u * 68 + (bi & 7) * 8 + j];
            ushort_t hh = f2bf(v);
            ov[j] = (bi < 8) ? (short)hh : (short)f2bf(v - bf2f(hh));
        }
        if (ok) {
            size_t base = (size_t)(grp * 16 + u) * 64;
            if (bi < 8) *(short8*)&hrow[base + bi * 8] = ov;
            else        *(short8*)&lrow[base + (bi - 8) * 8] = ov;
        }
    }
}

// ================= CSR build: two-level bucket sort, etype-segmented =================
__global__ __launch_bounds__(256) void k_bhist(const int* __restrict__ dst,
        int* __restrict__ bhist) {
    __shared__ int h[NBKT];
    for (int i = threadIdx.x; i < NBKT; i += 256) h[i] = 0;
    __syncthreads();
    int idx = blockIdx.x * 256 + threadIdx.x;
    for (int e = idx; e < N_EDGES; e += 256 * 256) atomicAdd(&h[dst[e] >> 7], 1);
    __syncthreads();
    for (int i = threadIdx.x; i < NBKT; i += 256) {
        int c = h[i];
        if (c) atomicAdd(&bhist[i], c);
    }
}

__global__ __launch_bounds__(1024) void k_bscan(const int* __restrict__ bhist,
        int* __restrict__ bbase, int* __restrict__ bcursor) {
    __shared__ int ts[NBKT];
    int t = threadIdx.x;
    int v = bhist[t];
    ts[t] = v;
    __syncthreads();
    for (int off = 1; off < NBKT; off <<= 1) {
        int u = (t >= off) ? ts[t - off] : 0;
        __syncthreads();
        ts[t] += u;
        __syncthreads();
    }
    int excl = ts[t] - v;
    bbase[t] = excl;
    bcursor[t] = excl;
    if (t == NBKT - 1) bbase[NBKT] = ts[NBKT - 1];
}

// payload: src(0..16) | et<<20 | (dst&127)<<22
__global__ __launch_bounds__(512) void k_bscatter(const int* __restrict__ src,
        const int* __restrict__ dst, const int* __restrict__ et,
        int* __restrict__ bcursor, unsigned int* __restrict__ ebuf) {
    __shared__ int hcnt[NBKT], loff[NBKT], gpos[NBKT], ps[512];
    __shared__ unsigned int stage[TILE_E];
    __shared__ unsigned short sbkt[TILE_E];
    int tid = threadIdx.x;
    int base = blockIdx.x * TILE_E;
    int tilecnt = min(TILE_E, N_EDGES - base);
    for (int i = tid; i < NBKT; i += 512) hcnt[i] = 0;
    __syncthreads();
    #pragma unroll
    for (int k = 0; k < TILE_E / 512; ++k) {
        int e = base + tid + k * 512;
        if (e < N_EDGES) atomicAdd(&hcnt[dst[e] >> 7], 1);
    }
    __syncthreads();
    int c0 = hcnt[tid * 2], c1 = hcnt[tid * 2 + 1];
    ps[tid] = c0 + c1;
    __syncthreads();
    for (int off = 1; off < 512; off <<= 1) {
        int u = (tid >= off) ? ps[tid - off] : 0;
        __syncthreads();
        ps[tid] += u;
        __syncthreads();
    }
    int ex = ps[tid] - (c0 + c1);
    loff[tid * 2] = ex;
    loff[tid * 2 + 1] = ex + c0;
    for (int b = tid; b < NBKT; b += 512) {
        int c = hcnt[b];
        gpos[b] = c ? atomicAdd(&bcursor[b], c) : 0;
    }
    __syncthreads();
    for (int i = tid; i < NBKT; i += 512) hcnt[i] = 0;
    __syncthreads();
    #pragma unroll
    for (int k = 0; k < TILE_E / 512; ++k) {
        int e = base + tid + k * 512;
        if (e < N_EDGES) {
            int d = dst[e];
            int b = d >> 7;
            int r = atomicAdd(&hcnt[b], 1);
            int lp = loff[b] + r;
            stage[lp] = (unsigned int)src[e] | ((unsigned int)et[e] << 20)
                      | ((unsigned int)(d & 127) << 22);
            sbkt[lp] = (unsigned short)b;
        }
    }
    __syncthreads();
    for (int i = tid; i < tilecnt; i += 512) {
        int b = sbkt[i];
        ebuf[gpos[b] + (i - loff[b])] = stage[i];
    }
}

// per-bucket: sort by (node,etype) -> adj (with node&31 embedded) + row_ptr2[n*4+t]
__global__ __launch_bounds__(256) void k_bcsr(const unsigned int* __restrict__ ebuf,
        const int* __restrict__ bbase, unsigned int* __restrict__ adj,
        int* __restrict__ row_ptr2) {
    __shared__ int ncnt[512], noff[513], ps[256];
    int b = blockIdx.x;
    int tid = threadIdx.x;
    int ebeg = bbase[b], eend = bbase[b + 1];
    int ecnt = eend - ebeg;
    ncnt[tid] = 0; ncnt[tid + 256] = 0;
    __syncthreads();
    for (int i = tid; i < ecnt; i += 256) {
        unsigned int p = ebuf[ebeg + i];
        int key = (int)((((p >> 22) & 127) << 2) | ((p >> 20) & 3));
        atomicAdd(&ncnt[key], 1);
    }
    __syncthreads();
    int c0 = ncnt[2 * tid], c1 = ncnt[2 * tid + 1];
    ps[tid] = c0 + c1;
    __syncthreads();
    for (int off = 1; off < 256; off <<= 1) {
        int u = (tid >= off) ? ps[tid - off] : 0;
        __syncthreads();
        ps[tid] += u;
        __syncthreads();
    }
    int ex = ps[tid] - (c0 + c1);
    noff[2 * tid] = ex;
    noff[2 * tid + 1] = ex + c0;
    if (tid == 255) noff[512] = ps[255];
    __syncthreads();
    ncnt[tid] = 0; ncnt[tid + 256] = 0;
    __syncthreads();
    for (int i = tid; i < ecnt; i += 256) {
        unsigned int p = ebuf[ebeg + i];
        int key = (int)((((p >> 22) & 127) << 2) | ((p >> 20) & 3));
        int r = atomicAdd(&ncnt[key], 1);
        adj[ebeg + noff[key] + r] = p & 0x07FFFFFFu;   // src | et<<20 | (node&31)<<22
    }
    for (int k = tid; k < 512; k += 256)
        row_ptr2[b * 512 + k] = ebeg + noff[k];
    if (b == NBKT - 1 && tid == 0) row_ptr2[NBKT * 512] = eend;
}

// ================= fused step: edge-parallel gather (LDS atomics) + transform + GRU =================
// 32 nodes/block, 512 threads = 8 waves, grid NGRP/2 = 3125.
__global__ __launch_bounds__(512) void k_step(const int* __restrict__ row_ptr2,
        const unsigned int* __restrict__ adj, const ushort_t* __restrict__ hin,
        const ushort_t* __restrict__ lin, ushort_t* __restrict__ hout,
        ushort_t* __restrict__ lout,
        const ushort_t* __restrict__ BC, const float* __restrict__ be,
        const ushort_t* __restrict__ B2, const float* __restrict__ bg2) {
    __shared__ float smem[8448];                        // aggf [32][260] f32 (33280 B)
    __shared__ int rp[129];                             // row_ptr2 slice for this block
    float* aggf = smem;
    ushort_t* als  = (ushort_t*)smem;                   // [32][136] (post-barrier alias)
    ushort_t* hlds = (ushort_t*)((char*)smem + 9216);   // [2][16][16][8]

    int tid = threadIdx.x, lane = tid & 63, wp = tid >> 6;
    int g = lane >> 4, u = lane & 15;
    int grp0 = blockIdx.x * 2;
    int nbase = grp0 * 16;

    // ---- Phase 0: zero aggf, stage row_ptr2 slice ----
    #pragma unroll
    for (int i = 0; i < 17; ++i) {
        int idx = i * 512 + tid;
        if (idx < 8320) aggf[idx] = 0.f;
    }
    if (tid < 129) rp[tid] = row_ptr2[nbase * 4 + tid];
    __syncthreads();

    // ---- Phase 1: flat edge-parallel gather; LDS f32 atomic accumulate ----
    {
        int E0 = rp[0], E1 = rp[128];
        int per = (E1 - E0 + 7) >> 3;
        int e0 = E0 + wp * per;
        int e1 = min(e0 + per, E1);
        int e = e0;
        for (; e + 8 <= e1; e += 8) {
            unsigned p0 = adj[e],     p1 = adj[e + 1], p2 = adj[e + 2], p3 = adj[e + 3];
            unsigned p4 = adj[e + 4], p5 = adj[e + 5], p6 = adj[e + 6], p7 = adj[e + 7];
            float v0 = bf2f(hin[(p0 & 0xFFFFFu) * 64u + (unsigned)lane]);
            float v1 = bf2f(hin[(p1 & 0xFFFFFu) * 64u + (unsigned)lane]);
            float v2 = bf2f(hin[(p2 & 0xFFFFFu) * 64u + (unsigned)lane]);
            float v3 = bf2f(hin[(p3 & 0xFFFFFu) * 64u + (unsigned)lane]);
            float v4 = bf2f(hin[(p4 & 0xFFFFFu) * 64u + (unsigned)lane]);
            float v5 = bf2f(hin[(p5 & 0xFFFFFu) * 64u + (unsigned)lane]);
            float v6 = bf2f(hin[(p6 & 0xFFFFFu) * 64u + (unsigned)lane]);
            float v7 = bf2f(hin[(p7 & 0xFFFFFu) * 64u + (unsigned)lane]);
            atomicAdd(&aggf[((p0 >> 22) & 31) * 260 + ((p0 >> 20) & 3) * 64 + lane], v0);
            atomicAdd(&aggf[((p1 >> 22) & 31) * 260 + ((p1 >> 20) & 3) * 64 + lane], v1);
            atomicAdd(&aggf[((p2 >> 22) & 31) * 260 + ((p2 >> 20) & 3) * 64 + lane], v2);
            atomicAdd(&aggf[((p3 >> 22) & 31) * 260 + ((p3 >> 20) & 3) * 64 + lane], v3);
            atomicAdd(&aggf[((p4 >> 22) & 31) * 260 + ((p4 >> 20) & 3) * 64 + lane], v4);
            atomicAdd(&aggf[((p5 >> 22) & 31) * 260 + ((p5 >> 20) & 3) * 64 + lane], v5);
            atomicAdd(&aggf[((p6 >> 22) & 31) * 260 + ((p6 >> 20) & 3) * 64 + lane], v6);
            atomicAdd(&aggf[((p7 >> 22) & 31) * 260 + ((p7 >> 20) & 3) * 64 + lane], v7);
        }
        for (; e < e1; ++e) {
            unsigned p = adj[e];
            float v = bf2f(hin[(p & 0xFFFFFu) * 64u + (unsigned)lane]);
            atomicAdd(&aggf[((p >> 22) & 31) * 260 + ((p >> 20) & 3) * 64 + lane], v);
        }
    }
    __syncthreads();

    // ---- Phase 2: MFMA1  a[32][64] = split3(agg[32][256]) x BC (trunc splits) ----
    int rp1 = wp >> 2, cq = wp & 3;
    f32x4 zero = {0.f, 0.f, 0.f, 0.f};
    f32x4 acc1 = zero;
    #pragma unroll
    for (int ks = 0; ks < 8; ++ks) {
        const float* ap = &aggf[(rp1 * 16 + u) * 260 + ks * 32 + g * 8];
        f32x4 x0 = *(const f32x4*)ap;
        f32x4 x1 = *(const f32x4*)(ap + 4);
        short8 ahi, alo;
        #pragma unroll
        for (int j = 0; j < 4; ++j) {
            unsigned b0 = __builtin_bit_cast(unsigned, x0[j]);
            ahi[j] = (short)(b0 >> 16);
            float l0 = x0[j] - __builtin_bit_cast(float, b0 & 0xFFFF0000u);
            alo[j] = (short)(__builtin_bit_cast(unsigned, l0) >> 16);
            unsigned b1 = __builtin_bit_cast(unsigned, x1[j]);
            ahi[4 + j] = (short)(b1 >> 16);
            float l1 = x1[j] - __builtin_bit_cast(float, b1 & 0xFFFF0000u);
            alo[4 + j] = (short)(__builtin_bit_cast(unsigned, l1) >> 16);
        }
        #pragma unroll
        for (int p = 0; p < 3; ++p) {
            short8 af = (p == 1) ? alo : ahi;
            short8 bf = *(const short8*)&BC[((size_t)((p * 8 + ks) * 4 + cq) * 64 + lane) * 8];
            acc1 = __builtin_amdgcn_mfma_f32_16x16x32_bf16(af, bf, acc1, 0, 0, 0);
        }
    }
    __syncthreads();   // aggf dead; als/hlds live below (rp separate)

    // ---- Phase 3a: a -> als (hi/lo trunc) + per-etype count x bias; stage own h ----
    {
        float beL[4];
        #pragma unroll
        for (int t = 0; t < 4; ++t) beL[t] = be[t * 64 + cq * 16 + u];
        #pragma unroll
        for (int j = 0; j < 4; ++j) {
            int row = rp1 * 16 + g * 4 + j;
            float c0 = (float)(rp[row * 4 + 1] - rp[row * 4 + 0]);
            float c1 = (float)(rp[row * 4 + 2] - rp[row * 4 + 1]);
            float c2 = (float)(rp[row * 4 + 3] - rp[row * 4 + 2]);
            float c3 = (float)(rp[row * 4 + 4] - rp[row * 4 + 3]);
            float v = acc1[j] + c0 * beL[0] + c1 * beL[1] + c2 * beL[2] + c3 * beL[3];
            int col = cq * 16 + u;
            unsigned bv = __builtin_bit_cast(unsigned, v);
            als[row * 136 + col] = (ushort_t)(bv >> 16);
            float lo = v - __builtin_bit_cast(float, bv & 0xFFFF0000u);
            als[row * 136 + 64 + col] = (ushort_t)(__builtin_bit_cast(unsigned, lo) >> 16);
        }
    }
    {
        int c = tid;                       // 0..511 -> 2 grp x 16 bi x 16 uu
        int gl = c >> 8, rr = c & 255, bi = rr >> 4, uu = rr & 15;
        size_t base = (size_t)(nbase + gl * 16 + uu) * 64;
        short8 v = (bi < 8) ? *(const short8*)&hin[base + bi * 8]
                            : *(const short8*)&lin[base + (bi - 8) * 8];
        *(short8*)&hlds[((gl * 16 + bi) * 16 + uu) * 8] = v;
    }
    __syncthreads();

    // ---- Phase 3b: MFMA2 gates[32][256] = split3([a|h]) x B2 ----
    int q = wp & 3, rp2 = wp >> 2;
    f32x4 acc2[4] = {zero, zero, zero, zero};
    #pragma unroll
    for (int s = 0; s < 12; ++s) {
        int p2 = s >> 2, ks2 = s & 3;
        short8 afr;
        if (ks2 < 2) {
            int base = ((p2 == 1) ? 64 : 0) + ks2 * 32 + g * 8;
            afr = *(const short8*)&als[(rp2 * 16 + u) * 136 + base];
        } else {
            int part = (p2 == 1) ? 1 : 0;
            int bi = part * 8 + (ks2 - 2) * 4 + g;
            afr = *(const short8*)&hlds[((rp2 * 16 + bi) * 16 + u) * 8];
        }
        #pragma unroll
        for (int ct = 0; ct < 4; ++ct) {
            short8 bfr = *(const short8*)&B2[((size_t)(s * 16 + q * 4 + ct) * 64 + g * 16 + u) * 8];
            acc2[ct] = __builtin_amdgcn_mfma_f32_16x16x32_bf16(afr, bfr, acc2[ct], 0, 0, 0);
        }
    }
    __syncthreads();   // all als/hlds reads done before hlds update

    // ---- Phase 4: GRU elementwise, update hlds in place (trunc split store) ----
    {
        float bgv[4];
        #pragma unroll
        for (int ct = 0; ct < 4; ++ct) bgv[ct] = bg2[q * 64 + ct * 16 + u];
        int hid = q * 16 + u;
        #pragma unroll
        for (int j = 0; j < 4; ++j) {
            int uu = g * 4 + j;
            int shi = ((rp2 * 16 + (hid >> 3)) * 16 + uu) * 8 + (hid & 7);
            int slo = ((rp2 * 16 + 8 + (hid >> 3)) * 16 + uu) * 8 + (hid & 7);
            float ho = bf2f(hlds[shi]) + bf2f(hlds[slo]);
            float rs  = acc2[0][j] + bgv[0];
            float zs  = acc2[1][j] + bgv[1];
            float inn = acc2[2][j] + bgv[2];
            float hnn = acc2[3][j] + bgv[3];
            float rr = 1.f / (1.f + __expf(-rs));
            float zz = 1.f / (1.f + __expf(-zs));
            float t = inn + rr * hnn;
            float e2 = __expf(2.f * t);
            float nn = 1.f - 2.f / (e2 + 1.f);
            float hnew = (1.f - zz) * nn + zz * ho;
            unsigned hb = __builtin_bit_cast(unsigned, hnew);
            hlds[shi] = (ushort_t)(hb >> 16);
            float lo2 = hnew - __builtin_bit_cast(float, hb & 0xFFFF0000u);
            hlds[slo] = (ushort_t)(__builtin_bit_cast(unsigned, lo2) >> 16);
        }
    }
    __syncthreads();

    // ---- pack-out: hlds -> hout/lout rows ----
    {
        int c = tid;                       // 0..511
        int gl = c >> 8, rr = c & 255, bi = rr >> 4, uu = rr & 15;
        short8 v = *(const short8*)&hlds[((gl * 16 + bi) * 16 + uu) * 8];
        size_t base = (size_t)(nbase + gl * 16 + uu) * 64;
        if (bi < 8) *(short8*)&hout[base + bi * 8] = v;
        else        *(short8*)&lout[base + (bi - 8) * 8] = v;
    }
}

// ---------------- per-graph mean pooling (reads hrow+lrow) ----------------
__global__ __launch_bounds__(256) void k_pool(const int* __restrict__ n2g,
        const ushort_t* __restrict__ hrow, const ushort_t* __restrict__ lrow,
        float* __restrict__ hg) {
    int gidx = blockIdx.x;
    int lo = 0, hi = N_NODES;
    while (lo < hi) { int mid = (lo + hi) >> 1; if (n2g[mid] < gidx) lo = mid + 1; else hi = mid; }
    int s = lo;
    hi = N_NODES;
    while (lo < hi) { int mid = (lo + hi) >> 1; if (n2g[mid] < gidx + 1) lo = mid + 1; else hi = mid; }
    int e = lo;
    int w = threadIdx.x >> 6, lane = threadIdx.x & 63;
    float sum = 0.f;
    for (int n = s + w; n < e; n += 4)
        sum += bf2f(hrow[(size_t)n * 64 + lane]) + bf2f(lrow[(size_t)n * 64 + lane]);
    __shared__ float red[4][64];
    red[w][lane] = sum;
    __syncthreads();
    if (threadIdx.x < 64) {
        float tot = red[0][lane] + red[1][lane] + red[2][lane] + red[3][lane];
        float cnt = (float)(e - s);
        hg[gidx * 64 + lane] = tot / fmaxf(cnt, 1.f);
    }
}

// ---------------- classifier ----------------
__global__ __launch_bounds__(64) void k_cls(const float* __restrict__ hg,
        const float* __restrict__ W1, const float* __restrict__ b1,
        const float* __restrict__ W2, const float* __restrict__ b2,
        float* __restrict__ out) {
    int gidx = blockIdx.x;
    __shared__ float v[64];
    __shared__ float m[32];
    v[threadIdx.x] = hg[gidx * 64 + threadIdx.x];
    __syncthreads();
    if (threadIdx.x < 32) {
        float a = b1[threadIdx.x];
        #pragma unroll 8
        for (int k = 0; k < 64; ++k) a = fmaf(v[k], W1[threadIdx.x * 64 + k], a);
        m[threadIdx.x] = fmaxf(a, 0.f);
    }
    __syncthreads();
    if (threadIdx.x < 10) {
        float a = b2[threadIdx.x];
        #pragma unroll
        for (int j = 0; j < 32; ++j) a = fmaf(m[j], W2[threadIdx.x * 32 + j], a);
        out[gidx * 10 + threadIdx.x] = a;
    }
}

extern "C" void kernel_launch(void* const* d_in, const int* in_sizes, int n_in,
                              void* d_out, int out_size, void* d_ws, size_t ws_size,
                              hipStream_t stream) {
    const float* x    = (const float*)d_in[0];
    const int* src    = (const int*)d_in[1];
    const int* dst    = (const int*)d_in[2];
    const int* etype  = (const int*)d_in[3];
    const int* n2g    = (const int*)d_in[4];
    const float* W_in = (const float*)d_in[5];
    const float* b_in = (const float*)d_in[6];
    const float* We   = (const float*)d_in[7];
    const float* be   = (const float*)d_in[8];
    const float* W_ih = (const float*)d_in[9];
    const float* b_ih = (const float*)d_in[10];
    const float* W_hh = (const float*)d_in[11];
    const float* b_hh = (const float*)d_in[12];
    const float* W1   = (const float*)d_in[13];
    const float* b1   = (const float*)d_in[14];
    const float* W2   = (const float*)d_in[15];
    const float* b2   = (const float*)d_in[16];
    float* out = (float*)d_out;

    char* wsb = (char*)d_ws;
    size_t off = 0;
    auto alloc = [&](size_t bytes) -> void* {
        void* p = wsb + off;
        off += (bytes + 255) & ~(size_t)255;
        return p;
    };
    ushort_t* hrowA    = (ushort_t*)alloc((size_t)N_NODES * 64 * 2);      // 12.8 MB
    ushort_t* lrowA    = (ushort_t*)alloc((size_t)N_NODES * 64 * 2);      // 12.8 MB
    ushort_t* hrowB    = (ushort_t*)alloc((size_t)N_NODES * 64 * 2);      // 12.8 MB
    ushort_t* lrowB    = (ushort_t*)alloc((size_t)N_NODES * 64 * 2);      // 12.8 MB
    unsigned int* adj  = (unsigned int*)alloc((size_t)N_EDGES * 4);
    unsigned int* ebuf = (unsigned int*)alloc((size_t)N_EDGES * 4);
    int*      row_ptr2 = (int*)     alloc(((size_t)NBKT * 512 + 1) * 4);  // 2.1 MB
    int*      bhist    = (int*)     alloc((size_t)NBKT * 4);
    int*      bbase    = (int*)     alloc((size_t)(NBKT + 1) * 4);
    int*      bcursor  = (int*)     alloc((size_t)NBKT * 4);
    ushort_t* B2       = (ushort_t*)alloc((size_t)12 * 16 * 4 * 16 * 8 * 2);
    float*    bg2      = (float*)   alloc(256 * 4);
    ushort_t* BIN      = (ushort_t*)alloc((size_t)24576 * 2);
    ushort_t* BC       = (ushort_t*)alloc((size_t)24 * 4 * 64 * 8 * 2);   // 96 KB
    float*    hg       = (float*)   alloc(128 * 64 * 4);

    hipLaunchKernelGGL(k_pack_b2, dim3(384), dim3(256), 0, stream, W_ih, b_ih, W_hh, b_hh, B2, bg2);
    hipLaunchKernelGGL(k_pack_bin, dim3(96), dim3(256), 0, stream, W_in, BIN);
    hipLaunchKernelGGL(k_pack_bc, dim3(192), dim3(256), 0, stream, We, BC);
    hipLaunchKernelGGL(k_linear_in, dim3((NGRP + 3) / 4), dim3(256), 0, stream, x, BIN, b_in, hrowA, lrowA);

    // CSR build via two-level bucket sort, (node,etype)-segmented
    hipMemsetAsync(bhist, 0, (size_t)NBKT * 4, stream);
    hipLaunchKernelGGL(k_bhist, dim3(256), dim3(256), 0, stream, dst, bhist);
    hipLaunchKernelGGL(k_bscan, dim3(1), dim3(1024), 0, stream, bhist, bbase, bcursor);
    hipLaunchKernelGGL(k_bscatter, dim3((N_EDGES + TILE_E - 1) / TILE_E), dim3(512), 0, stream,
                       src, dst, etype, bcursor, ebuf);
    hipLaunchKernelGGL(k_bcsr, dim3(NBKT), dim3(256), 0, stream, ebuf, bbase, adj, row_ptr2);

    int sblk = NGRP / 2;   // 3125
    for (int step = 0; step < STEPS; ++step) {
        const ushort_t* hin = (step & 1) ? hrowB : hrowA;
        const ushort_t* lin = (step & 1) ? lrowB : lrowA;
        ushort_t* hout      = (step & 1) ? hrowA : hrowB;
        ushort_t* lout      = (step & 1) ? lrowA : lrowB;
        hipLaunchKernelGGL(k_step, dim3(sblk), dim3(512), 0, stream,
                           row_ptr2, adj, hin, lin, hout, lout, BC, be, B2, bg2);
    }
    hipLaunchKernelGGL(k_pool, dim3(G_GRAPHS), dim3(256), 0, stream, n2g, hrowB, lrowB, hg);
    hipLaunchKernelGGL(k_cls, dim3(G_GRAPHS), dim3(64), 0, stream, hg, W1, b1, W2, b2, out);
}